// Round 5
// baseline (1982.980 us; speedup 1.0000x reference)
//
#include <hip/hip_runtime.h>
#include <hip/hip_bf16.h>

#define H_ 224
#define W_ 224
#define C_ 64
#define F_ 256

typedef __attribute__((ext_vector_type(8))) short bf16x8;
typedef __attribute__((ext_vector_type(4))) float f32x4;

__device__ __forceinline__ unsigned short f2bf(float f) {
  union { float f; unsigned int u; } c; c.f = f;
  unsigned int u = c.u;
  return (unsigned short)((u + 0x7fffu + ((u >> 16) & 1u)) >> 16);
}

// Pre-pack U2 = Unp1 @ S into MFMA B-fragment layout [18][8][64][8] (N padded to 128),
// and Vt into [4][16][64][8] (K padded to 128).  (unchanged from R2 — verified)
__global__ __launch_bounds__(256) void prep_kernel(
    const float* __restrict__ Unp1, const float* __restrict__ S,
    const float* __restrict__ Vt,
    unsigned short* __restrict__ uFrag, unsigned short* __restrict__ vFrag) {
  int u = blockIdx.x * 256 + threadIdx.x;
  if (u < 576 * 128) {
    int k = u >> 7;       // 0..575
    int n = u & 127;      // 0..127
    float acc = 0.f;
    if (n < 100) {
      for (int q = 0; q < 100; ++q)
        acc += Unp1[k * 100 + q] * S[q * 100 + n];
    }
    int ks = k >> 5, kk = k & 31, g = kk >> 3, j = kk & 7;
    int nt = n >> 4, lm = n & 15;
    uFrag[(((ks * 8 + nt) * 64) + g * 16 + lm) * 8 + j] = f2bf(acc);
  } else {
    int u2 = u - 576 * 128;
    if (u2 < 4 * 16 * 64 * 8) {
      int j = u2 & 7;
      int lane = (u2 >> 3) & 63;
      int nt = (u2 >> 9) & 15;
      int ks = u2 >> 13;
      int k = ks * 32 + (lane >> 4) * 8 + j;
      int n = nt * 16 + (lane & 15);
      float v = (k < 100) ? Vt[k * 256 + n] : 0.f;
      vFrag[u2] = f2bf(v);
    }
  }
}

// Persistent-tile fused kernel: one block owns tile (th, w0..w0+31) and loops
// over all 8 images. Bias lives in registers across the loop; weights become
// L2-hot via immediate reuse. 2 barriers per image-iteration.
__global__ __launch_bounds__(256, 3) void conv_kernel(
    const float* __restrict__ x,
    const unsigned short* __restrict__ uFrag,
    const unsigned short* __restrict__ vFrag,
    const float* __restrict__ bias,
    float* __restrict__ out) {
  __shared__ unsigned short xt[3 * 34 * 64];   // 13056 B, XOR-swizzled
  __shared__ unsigned short z1[32 * 128];      // 8192 B, XOR-swizzled

  int bid = blockIdx.x;
  // XCD-banded tile mapping: xcd = bid%8 owns th-band [xcd*28, xcd*28+28)
  // so halo-sharing th-neighbors live on the same XCD's L2.
  int xcd = bid & 7;
  int idx = bid >> 3;               // 0..195
  int tw = idx / 28;                // 0..6
  int th = xcd * 28 + (idx % 28);   // 0..223
  int w0 = tw * 32;

  int tid = threadIdx.x;
  int lane = tid & 63, wid = tid >> 6;
  int wm = wid & 1, wn = wid >> 1;
  int g = lane >> 4, lm = lane & 15;
  int wbase = w0 + wm * 16;

  // ---- bias -> 32 registers, once per block (reused for all 8 images) ----
  float bv[8][4];
  #pragma unroll
  for (int j = 0; j < 8; ++j)
    #pragma unroll
    for (int i = 0; i < 4; ++i) {
      int r = th * W_ + wbase + g * 4 + i;
      bv[j][i] = bias[(size_t)r * F_ + (wn * 8 + j) * 16 + lm];
    }

  for (int bb = 0; bb < 8; ++bb) {
    // ---- stage x halo (3 rows x 34 cols x 64 ch) -> LDS bf16, swizzled ----
    // SYNC note: reaching here means this wave finished the previous image's
    // G2 (z1 reads) and stores; the syncthreads below also orders all other
    // waves' z1/xt accesses.
    const float* xb = x + (size_t)bb * (H_ * W_ * C_);
    #pragma unroll
    for (int it = 0; it < 4; ++it) {
      int i = tid + it * 256;
      if (i < 816) {                    // 3*34*8 chunks of 8 channels
        int row34 = i >> 3, c8 = i & 7;
        int kh = row34 / 34;
        int ww = row34 - kh * 34;
        int h = th - 1 + kh, w = w0 - 1 + ww;
        bf16x8 sv;
        if (h >= 0 && h < H_ && w >= 0 && w < W_) {
          const float* p = xb + ((size_t)(h * W_ + w)) * C_ + c8 * 8;
          float4 f0 = *(const float4*)p;
          float4 f1 = *(const float4*)(p + 4);
          sv[0] = (short)f2bf(f0.x); sv[1] = (short)f2bf(f0.y);
          sv[2] = (short)f2bf(f0.z); sv[3] = (short)f2bf(f0.w);
          sv[4] = (short)f2bf(f1.x); sv[5] = (short)f2bf(f1.y);
          sv[6] = (short)f2bf(f1.z); sv[7] = (short)f2bf(f1.w);
        } else {
          sv = (bf16x8){0, 0, 0, 0, 0, 0, 0, 0};
        }
        *(bf16x8*)&xt[row34 * 64 + ((c8 ^ (row34 & 7)) << 3)] = sv;
      }
    }
    __syncthreads();   // SYNC0: xt ready; also fences prev iter's z1 reads

    // ---- GEMM1: patches(32x576) @ U2 -> acc1 (barrier-free, reg-dbuf) ----
    f32x4 acc1[4] = {};
    {
      // explicit even/odd double-buffered fragments for ILP
      bf16x8 ae, ao, be[4], bo[4];
      {
        int row34 = 0 * 34 + wbase - w0 + lm + 0;   // ks=0: kh=0, kw=0
        int chunk = (0 + g) ^ (row34 & 7);
        ae = *(const bf16x8*)&xt[row34 * 64 + chunk * 8];
        #pragma unroll
        for (int jj = 0; jj < 4; ++jj)
          be[jj] = *(const bf16x8*)&uFrag[(((0 * 8 + wn * 4 + jj) * 64) + lane) * 8];
      }
      #pragma unroll
      for (int ks = 0; ks < 18; ++ks) {
        bool even = (ks & 1) == 0;
        if (ks < 17) {
          int kn = ks + 1;
          int cell = kn >> 1;
          int kh = cell / 3, kw = cell - kh * 3;
          int row34 = kh * 34 + (wm * 16 + lm) + kw;
          int chunk = ((kn & 1) * 4 + g) ^ (row34 & 7);
          bf16x8 a_n = *(const bf16x8*)&xt[row34 * 64 + chunk * 8];
          if (even) ao = a_n; else ae = a_n;
          #pragma unroll
          for (int jj = 0; jj < 4; ++jj) {
            bf16x8 b_n = *(const bf16x8*)&uFrag[(((kn * 8 + wn * 4 + jj) * 64) + lane) * 8];
            if (even) bo[jj] = b_n; else be[jj] = b_n;
          }
        }
        #pragma unroll
        for (int jj = 0; jj < 4; ++jj) {
          bf16x8 a_c = even ? ae : ao;
          bf16x8 b_c = even ? be[jj] : bo[jj];
          acc1[jj] = __builtin_amdgcn_mfma_f32_16x16x32_bf16(a_c, b_c, acc1[jj], 0, 0, 0);
        }
      }
    }

    // ---- z1 -> LDS (bf16, swizzled) ----
    #pragma unroll
    for (int jj = 0; jj < 4; ++jj) {
      int col = (wn * 4 + jj) * 16 + lm;
      #pragma unroll
      for (int i = 0; i < 4; ++i) {
        int row = wm * 16 + g * 4 + i;
        z1[row * 128 + (((col >> 3) ^ (row & 7)) << 3) + (col & 7)] = f2bf(acc1[jj][i]);
      }
    }
    __syncthreads();   // SYNC1: z1 ready; all xt reads done

    // ---- GEMM2: z1(32x128) @ Vt(128x256), A hoisted, 8-wide B ILP ----
    f32x4 acc2[8] = {};
    bf16x8 a2[4];
    #pragma unroll
    for (int ks = 0; ks < 4; ++ks) {
      int row = wm * 16 + lm;
      int chunk = (ks * 4 + g) ^ (row & 7);
      a2[ks] = *(const bf16x8*)&z1[row * 128 + chunk * 8];
    }
    #pragma unroll
    for (int ks = 0; ks < 4; ++ks) {
      bf16x8 bq[8];
      #pragma unroll
      for (int j = 0; j < 8; ++j)
        bq[j] = *(const bf16x8*)&vFrag[(((ks * 16 + wn * 8 + j) * 64) + lane) * 8];
      #pragma unroll
      for (int j = 0; j < 8; ++j)
        acc2[j] = __builtin_amdgcn_mfma_f32_16x16x32_bf16(a2[ks], bq[j], acc2[j], 0, 0, 0);
    }

    // ---- bias + relu + store (i outer, j inner: j-pairs fill 128B lines) ----
    float* ob = out + (size_t)bb * (H_ * W_ * F_) +
                ((size_t)(th * W_) + wbase) * F_;
    #pragma unroll
    for (int i = 0; i < 4; ++i) {
      int woff = g * 4 + i;
      #pragma unroll
      for (int j = 0; j < 8; ++j) {
        float v = fmaxf(acc2[j][i] + bv[j][i], 0.f);
        ob[(size_t)woff * F_ + (wn * 8 + j) * 16 + lm] = v;
      }
    }
    // no barrier needed here: next iter's SYNC0 orders xt/z1 reuse
  }
}

extern "C" void kernel_launch(void* const* d_in, const int* in_sizes, int n_in,
                              void* d_out, int out_size, void* d_ws, size_t ws_size,
                              hipStream_t stream) {
  const float* x     = (const float*)d_in[0];
  const float* S     = (const float*)d_in[3];
  const float* Unp1  = (const float*)d_in[5];
  const float* Vtnp1 = (const float*)d_in[7];
  const float* bias  = (const float*)d_in[8];
  float* out = (float*)d_out;

  unsigned short* uFrag = (unsigned short*)d_ws;                    // 147456 B
  unsigned short* vFrag = (unsigned short*)((char*)d_ws + 18 * 8 * 64 * 8 * 2);  // 65536 B

  hipLaunchKernelGGL(prep_kernel, dim3(416), dim3(256), 0, stream,
                     Unp1, S, Vtnp1, uFrag, vFrag);
  hipLaunchKernelGGL(conv_kernel, dim3(224 * 7), dim3(256), 0, stream,
                     x, uFrag, vFrag, bias, out);
}

// Round 6
// 833.838 us; speedup vs baseline: 2.3781x; 2.3781x over previous
//
#include <hip/hip_runtime.h>
#include <hip/hip_bf16.h>

#define H_ 224
#define W_ 224
#define C_ 64
#define F_ 256

typedef __attribute__((ext_vector_type(8))) short bf16x8;
typedef __attribute__((ext_vector_type(4))) float f32x4;

__device__ __forceinline__ unsigned short f2bf(float f) {
  union { float f; unsigned int u; } c; c.f = f;
  unsigned int u = c.u;
  return (unsigned short)((u + 0x7fffu + ((u >> 16) & 1u)) >> 16);
}

// Pre-pack U2 = Unp1 @ S into MFMA B-fragment layout [18][8][64][8] (N padded to 128),
// and Vt into [4][16][64][8] (K padded to 128).  (verified R2)
__global__ __launch_bounds__(256) void prep_kernel(
    const float* __restrict__ Unp1, const float* __restrict__ S,
    const float* __restrict__ Vt,
    unsigned short* __restrict__ uFrag, unsigned short* __restrict__ vFrag) {
  int u = blockIdx.x * 256 + threadIdx.x;
  if (u < 576 * 128) {
    int k = u >> 7;       // 0..575
    int n = u & 127;      // 0..127
    float acc = 0.f;
    if (n < 100) {
      for (int q = 0; q < 100; ++q)
        acc += Unp1[k * 100 + q] * S[q * 100 + n];
    }
    int ks = k >> 5, kk = k & 31, g = kk >> 3, j = kk & 7;
    int nt = n >> 4, lm = n & 15;
    uFrag[(((ks * 8 + nt) * 64) + g * 16 + lm) * 8 + j] = f2bf(acc);
  } else {
    int u2 = u - 576 * 128;
    if (u2 < 4 * 16 * 64 * 8) {
      int j = u2 & 7;
      int lane = (u2 >> 3) & 63;
      int nt = (u2 >> 9) & 15;
      int ks = u2 >> 13;
      int k = ks * 32 + (lane >> 4) * 8 + j;
      int n = nt * 16 + (lane & 15);
      float v = (k < 100) ? Vt[k * 256 + n] : 0.f;
      vFrag[u2] = f2bf(v);
    }
  }
}

// Fused: per block, tile = 2 rows x 32 cols of one image (R2 structure).
// GEMM1: patches(64x576) @ U2(576x128) -> z1 (LDS, bf16)  [B-frag reg-dbuf]
// GEMM2: z1(64x128) @ Vt(128x256) + bias -> relu -> out   [plain stores]
__global__ __launch_bounds__(256, 4) void conv_kernel(
    const float* __restrict__ x,
    const unsigned short* __restrict__ uFrag,
    const unsigned short* __restrict__ vFrag,
    const float* __restrict__ bias,
    float* __restrict__ out) {
  __shared__ unsigned short xt[4 * 34 * 64];   // x halo tile, XOR-swizzled
  __shared__ unsigned short z1[64 * 128];      // intermediate, XOR-swizzled

  int bid = blockIdx.x;
  // bb FASTEST: 8 consecutive blocks = same tile across 8 images -> bias/weight
  // lines shared via L2/L3 among concurrently-running blocks.
  int bb = bid & 7;
  int t2 = bid >> 3;
  int tw = t2 % 7;
  int th = t2 / 7;
  int h0 = th * 2, w0 = tw * 32;
  int tid = threadIdx.x;
  int lane = tid & 63, wid = tid >> 6;
  int wm = wid & 1, wn = wid >> 1;
  int g = lane >> 4, lm = lane & 15;

  // ---- stage x halo tile -> LDS bf16 (swizzled: chunk ^= row&7) ----
  const float* xb = x + (size_t)bb * (H_ * W_ * C_);
  #pragma unroll
  for (int it = 0; it < 5; ++it) {
    int i = tid + it * 256;
    if (i < 1088) {                       // 4*34*8 chunks of 8 elems
      int row34 = i >> 3, c8 = i & 7;
      int r = row34 / 34;
      int ww = row34 - r * 34;
      int h = h0 - 1 + r, w = w0 - 1 + ww;
      bf16x8 sv;
      if (h >= 0 && h < H_ && w >= 0 && w < W_) {
        const float* p = xb + ((size_t)(h * W_ + w)) * C_ + c8 * 8;
        float4 f0 = *(const float4*)p;
        float4 f1 = *(const float4*)(p + 4);
        sv[0] = (short)f2bf(f0.x); sv[1] = (short)f2bf(f0.y);
        sv[2] = (short)f2bf(f0.z); sv[3] = (short)f2bf(f0.w);
        sv[4] = (short)f2bf(f1.x); sv[5] = (short)f2bf(f1.y);
        sv[6] = (short)f2bf(f1.z); sv[7] = (short)f2bf(f1.w);
      } else {
        sv = (bf16x8){0, 0, 0, 0, 0, 0, 0, 0};
      }
      *(bf16x8*)&xt[row34 * 64 + ((c8 ^ (row34 & 7)) << 3)] = sv;
    }
  }

  // per-thread output row offsets (h*W + w) for the 8 rows this thread owns
  int rowoff[2][4];
  #pragma unroll
  for (int t = 0; t < 2; ++t) {
    #pragma unroll
    for (int i = 0; i < 4; ++i) {
      int mrow = (2 * wm + t) * 16 + g * 4 + i;
      int dh = mrow >> 5, dw = mrow & 31;
      rowoff[t][i] = (h0 + dh) * W_ + (w0 + dw);
    }
  }

  __syncthreads();

  // ---- bias prefetch, first half (f = (wn*8+j)*16+lm, j=0..3) ----
  float bv0[2][4][4];
  #pragma unroll
  for (int t = 0; t < 2; ++t)
    #pragma unroll
    for (int j = 0; j < 4; ++j)
      #pragma unroll
      for (int i = 0; i < 4; ++i)
        bv0[t][j][i] = bias[(size_t)rowoff[t][i] * F_ + (wn * 8 + j) * 16 + lm];

  // ---- GEMM1 with 2-deep register double-buffer on the uFrag B-frags ----
  f32x4 acc1[2][4] = {};
  {
    bf16x8 bcur[4], bnext[4];
    #pragma unroll
    for (int jj = 0; jj < 4; ++jj)
      bcur[jj] = *(const bf16x8*)&uFrag[(((0 * 8 + wn * 4 + jj) * 64) + lane) * 8];
    #pragma unroll
    for (int ks = 0; ks < 18; ++ks) {
      if (ks < 17) {
        #pragma unroll
        for (int jj = 0; jj < 4; ++jj)
          bnext[jj] = *(const bf16x8*)&uFrag[((((ks + 1) * 8 + wn * 4 + jj) * 64) + lane) * 8];
      }
      int cell = ks >> 1;
      int kh = cell / 3, kw = cell - kh * 3;
      int c0c = (ks & 1) * 4;             // chunk offset within row (units of 8 elems)
      bf16x8 a[2];
      #pragma unroll
      for (int t = 0; t < 2; ++t) {
        int mrow = (2 * wm + t) * 16 + lm;  // 0..63
        int dh = mrow >> 5, dw = mrow & 31;
        int row34 = (dh + kh) * 34 + dw + kw;
        int chunk = (c0c + g) ^ (row34 & 7);
        a[t] = *(const bf16x8*)&xt[row34 * 64 + chunk * 8];
      }
      #pragma unroll
      for (int jj = 0; jj < 4; ++jj) {
        acc1[0][jj] = __builtin_amdgcn_mfma_f32_16x16x32_bf16(a[0], bcur[jj], acc1[0][jj], 0, 0, 0);
        acc1[1][jj] = __builtin_amdgcn_mfma_f32_16x16x32_bf16(a[1], bcur[jj], acc1[1][jj], 0, 0, 0);
      }
      if (ks < 17) {
        #pragma unroll
        for (int jj = 0; jj < 4; ++jj)
          bcur[jj] = bnext[jj];
      }
    }
  }

  // ---- z1 -> LDS (bf16, swizzled) ----
  #pragma unroll
  for (int jj = 0; jj < 4; ++jj) {
    int col = (wn * 4 + jj) * 16 + lm;
    #pragma unroll
    for (int i = 0; i < 4; ++i) {
      int row = (2 * wm + 0) * 16 + g * 4 + i;
      z1[row * 128 + (((col >> 3) ^ (row & 7)) << 3) + (col & 7)] = f2bf(acc1[0][jj][i]);
      int row1 = (2 * wm + 1) * 16 + g * 4 + i;
      z1[row1 * 128 + (((col >> 3) ^ (row1 & 7)) << 3) + (col & 7)] = f2bf(acc1[1][jj][i]);
    }
  }
  __syncthreads();

  // ---- bias prefetch, second half (j=4..7); hidden under GEMM2 half 0 ----
  float bv1[2][4][4];
  #pragma unroll
  for (int t = 0; t < 2; ++t)
    #pragma unroll
    for (int j = 0; j < 4; ++j)
      #pragma unroll
      for (int i = 0; i < 4; ++i)
        bv1[t][j][i] = bias[(size_t)rowoff[t][i] * F_ + (wn * 8 + 4 + j) * 16 + lm];

  float* ob = out + (size_t)bb * (H_ * W_ * F_);

  // ---- GEMM2 half 0 (j = 0..3) ----
  {
    f32x4 acc2[2][4] = {};
    bf16x8 a2[2][4];
    #pragma unroll
    for (int ks = 0; ks < 4; ++ks) {
      #pragma unroll
      for (int t = 0; t < 2; ++t) {
        int row = (2 * wm + t) * 16 + lm;
        int chunk = (ks * 4 + g) ^ (row & 7);
        a2[t][ks] = *(const bf16x8*)&z1[row * 128 + chunk * 8];
      }
    }
    #pragma unroll
    for (int ks = 0; ks < 4; ++ks) {
      bf16x8 bq[4];
      #pragma unroll
      for (int j = 0; j < 4; ++j)
        bq[j] = *(const bf16x8*)&vFrag[(((ks * 16 + wn * 8 + j) * 64) + lane) * 8];
      #pragma unroll
      for (int j = 0; j < 4; ++j) {
        acc2[0][j] = __builtin_amdgcn_mfma_f32_16x16x32_bf16(a2[0][ks], bq[j], acc2[0][j], 0, 0, 0);
        acc2[1][j] = __builtin_amdgcn_mfma_f32_16x16x32_bf16(a2[1][ks], bq[j], acc2[1][j], 0, 0, 0);
      }
    }
    #pragma unroll
    for (int t = 0; t < 2; ++t)
      #pragma unroll
      for (int j = 0; j < 4; ++j) {
        int f = (wn * 8 + j) * 16 + lm;
        #pragma unroll
        for (int i = 0; i < 4; ++i) {
          float v = fmaxf(acc2[t][j][i] + bv0[t][j][i], 0.f);
          ob[(size_t)rowoff[t][i] * F_ + f] = v;
        }
      }
  }

  // ---- GEMM2 half 1 (j = 4..7) ----
  {
    f32x4 acc2[2][4] = {};
    bf16x8 a2[2][4];
    #pragma unroll
    for (int ks = 0; ks < 4; ++ks) {
      #pragma unroll
      for (int t = 0; t < 2; ++t) {
        int row = (2 * wm + t) * 16 + lm;
        int chunk = (ks * 4 + g) ^ (row & 7);
        a2[t][ks] = *(const bf16x8*)&z1[row * 128 + chunk * 8];
      }
    }
    #pragma unroll
    for (int ks = 0; ks < 4; ++ks) {
      bf16x8 bq[4];
      #pragma unroll
      for (int j = 0; j < 4; ++j)
        bq[j] = *(const bf16x8*)&vFrag[(((ks * 16 + wn * 8 + 4 + j) * 64) + lane) * 8];
      #pragma unroll
      for (int j = 0; j < 4; ++j) {
        acc2[0][j] = __builtin_amdgcn_mfma_f32_16x16x32_bf16(a2[0][ks], bq[j], acc2[0][j], 0, 0, 0);
        acc2[1][j] = __builtin_amdgcn_mfma_f32_16x16x32_bf16(a2[1][ks], bq[j], acc2[1][j], 0, 0, 0);
      }
    }
    #pragma unroll
    for (int t = 0; t < 2; ++t)
      #pragma unroll
      for (int j = 0; j < 4; ++j) {
        int f = (wn * 8 + 4 + j) * 16 + lm;
        #pragma unroll
        for (int i = 0; i < 4; ++i) {
          float v = fmaxf(acc2[t][j][i] + bv1[t][j][i], 0.f);
          ob[(size_t)rowoff[t][i] * F_ + f] = v;
        }
      }
  }
}

extern "C" void kernel_launch(void* const* d_in, const int* in_sizes, int n_in,
                              void* d_out, int out_size, void* d_ws, size_t ws_size,
                              hipStream_t stream) {
  const float* x     = (const float*)d_in[0];
  const float* S     = (const float*)d_in[3];
  const float* Unp1  = (const float*)d_in[5];
  const float* Vtnp1 = (const float*)d_in[7];
  const float* bias  = (const float*)d_in[8];
  float* out = (float*)d_out;

  unsigned short* uFrag = (unsigned short*)d_ws;                    // 147456 B
  unsigned short* vFrag = (unsigned short*)((char*)d_ws + 18 * 8 * 64 * 8 * 2);  // 65536 B

  hipLaunchKernelGGL(prep_kernel, dim3(416), dim3(256), 0, stream,
                     Unp1, S, Vtnp1, uFrag, vFrag);
  hipLaunchKernelGGL(conv_kernel, dim3(8 * 112 * 7), dim3(256), 0, stream,
                     x, uFrag, vFrag, bias, out);
}

// Round 7
// 735.781 us; speedup vs baseline: 2.6951x; 1.1333x over previous
//
#include <hip/hip_runtime.h>
#include <hip/hip_bf16.h>

#define H_ 224
#define W_ 224
#define C_ 64
#define F_ 256
#define NPIX 50176      // H_*W_
#define ZSTR 128        // z row stride (elements)

typedef __attribute__((ext_vector_type(8))) short bf16x8;
typedef __attribute__((ext_vector_type(4))) float f32x4;

__device__ __forceinline__ unsigned short f2bf(float f) {
  union { float f; unsigned int u; } c; c.f = f;
  unsigned int u = c.u;
  return (unsigned short)((u + 0x7fffu + ((u >> 16) & 1u)) >> 16);
}

// Pre-pack U2 = Unp1 @ S into MFMA B-fragment layout [18][8][64][8] (N padded to 128),
// and Vt into [4][16][64][8] (K padded to 128).  (verified R2)
__global__ __launch_bounds__(256) void prep_kernel(
    const float* __restrict__ Unp1, const float* __restrict__ S,
    const float* __restrict__ Vt,
    unsigned short* __restrict__ uFrag, unsigned short* __restrict__ vFrag) {
  int u = blockIdx.x * 256 + threadIdx.x;
  if (u < 576 * 128) {
    int k = u >> 7;       // 0..575
    int n = u & 127;      // 0..127
    float acc = 0.f;
    if (n < 100) {
      for (int q = 0; q < 100; ++q)
        acc += Unp1[k * 100 + q] * S[q * 100 + n];
    }
    int ks = k >> 5, kk = k & 31, g = kk >> 3, j = kk & 7;
    int nt = n >> 4, lm = n & 15;
    uFrag[(((ks * 8 + nt) * 64) + g * 16 + lm) * 8 + j] = f2bf(acc);
  } else {
    int u2 = u - 576 * 128;
    if (u2 < 4 * 16 * 64 * 8) {
      int j = u2 & 7;
      int lane = (u2 >> 3) & 63;
      int nt = (u2 >> 9) & 15;
      int ks = u2 >> 13;
      int k = ks * 32 + (lane >> 4) * 8 + j;
      int n = nt * 16 + (lane & 15);
      float v = (k < 100) ? Vt[k * 256 + n] : 0.f;
      vFrag[u2] = f2bf(v);
    }
  }
}

// ---------- Kernel A: z = patches @ U2 (bf16 out, cols 100..127 = 0) ----------
__global__ __launch_bounds__(256, 4) void g1_kernel(
    const float* __restrict__ x,
    const unsigned short* __restrict__ uFrag,
    unsigned short* __restrict__ z) {
  __shared__ unsigned short xt[4 * 34 * 64];   // halo tile, XOR-swizzled
  __shared__ unsigned short z1[64 * 128];      // result staging, XOR-swizzled

  int bid = blockIdx.x;
  int tw = bid % 7;
  int th = (bid / 7) % 112;
  int bb = bid / 784;                  // bb slowest: adjacent blocks share x halo
  int h0 = th * 2, w0 = tw * 32;
  int tid = threadIdx.x;
  int lane = tid & 63, wid = tid >> 6;
  int wm = wid & 1, wn = wid >> 1;
  int g = lane >> 4, lm = lane & 15;

  // ---- stage x halo tile -> LDS bf16 (verified R2) ----
  const float* xb = x + (size_t)bb * (H_ * W_ * C_);
  #pragma unroll
  for (int it = 0; it < 5; ++it) {
    int i = tid + it * 256;
    if (i < 1088) {
      int row34 = i >> 3, c8 = i & 7;
      int r = row34 / 34;
      int ww = row34 - r * 34;
      int h = h0 - 1 + r, w = w0 - 1 + ww;
      bf16x8 sv;
      if (h >= 0 && h < H_ && w >= 0 && w < W_) {
        const float* p = xb + ((size_t)(h * W_ + w)) * C_ + c8 * 8;
        float4 f0 = *(const float4*)p;
        float4 f1 = *(const float4*)(p + 4);
        sv[0] = (short)f2bf(f0.x); sv[1] = (short)f2bf(f0.y);
        sv[2] = (short)f2bf(f0.z); sv[3] = (short)f2bf(f0.w);
        sv[4] = (short)f2bf(f1.x); sv[5] = (short)f2bf(f1.y);
        sv[6] = (short)f2bf(f1.z); sv[7] = (short)f2bf(f1.w);
      } else {
        sv = (bf16x8){0, 0, 0, 0, 0, 0, 0, 0};
      }
      *(bf16x8*)&xt[row34 * 64 + ((c8 ^ (row34 & 7)) << 3)] = sv;
    }
  }
  __syncthreads();

  // ---- GEMM1 (verified R2) ----
  f32x4 acc1[2][4] = {};
  #pragma unroll
  for (int ks = 0; ks < 18; ++ks) {
    int cell = ks >> 1;
    int kh = cell / 3, kw = cell - kh * 3;
    int c0c = (ks & 1) * 4;
    bf16x8 a[2];
    #pragma unroll
    for (int t = 0; t < 2; ++t) {
      int mrow = (2 * wm + t) * 16 + lm;
      int dh = mrow >> 5, dw = mrow & 31;
      int row34 = (dh + kh) * 34 + dw + kw;
      int chunk = (c0c + g) ^ (row34 & 7);
      a[t] = *(const bf16x8*)&xt[row34 * 64 + chunk * 8];
    }
    #pragma unroll
    for (int j = 0; j < 4; ++j) {
      int nt = wn * 4 + j;
      bf16x8 bq = *(const bf16x8*)&uFrag[(((ks * 8 + nt) * 64) + lane) * 8];
      acc1[0][j] = __builtin_amdgcn_mfma_f32_16x16x32_bf16(a[0], bq, acc1[0][j], 0, 0, 0);
      acc1[1][j] = __builtin_amdgcn_mfma_f32_16x16x32_bf16(a[1], bq, acc1[1][j], 0, 0, 0);
    }
  }

  // ---- acc -> z1 LDS (bf16, swizzled; verified R2) ----
  #pragma unroll
  for (int t = 0; t < 2; ++t) {
    #pragma unroll
    for (int j = 0; j < 4; ++j) {
      int col = (wn * 4 + j) * 16 + lm;
      #pragma unroll
      for (int i = 0; i < 4; ++i) {
        int row = (2 * wm + t) * 16 + g * 4 + i;
        z1[row * 128 + (((col >> 3) ^ (row & 7)) << 3) + (col & 7)] = f2bf(acc1[t][j][i]);
      }
    }
  }
  __syncthreads();

  // ---- cooperative z1 -> z (coalesced 16B stores) ----
  #pragma unroll
  for (int it = 0; it < 4; ++it) {
    int i = tid + it * 256;            // 0..1023
    int row = i >> 4, c8 = i & 15;
    bf16x8 v = *(const bf16x8*)&z1[row * 128 + ((c8 ^ (row & 7)) << 3)];
    int pixel = (h0 + (row >> 5)) * W_ + w0 + (row & 31);
    *(bf16x8*)&z[((size_t)bb * NPIX + pixel) * ZSTR + c8 * 8] = v;
  }
}

// ---------- Kernel B: out = relu(z @ Vt + bias) ----------
// Block = 32 pixels x 256 f, loops 8 images. B-frags + bias in registers.
__global__ __launch_bounds__(256, 2) void g2_kernel(
    const unsigned short* __restrict__ z,
    const unsigned short* __restrict__ vFrag,
    const float* __restrict__ bias,
    float* __restrict__ out) {
  int chunk = blockIdx.x;              // 0..1567, 32 consecutive pixels
  int tid = threadIdx.x;
  int lane = tid & 63, w = tid >> 6;   // wave -> f-range [w*64, w*64+64)
  int g = lane >> 4, lm = lane & 15;

  // B fragments, held all-kernel: 16 x 16B from L2
  bf16x8 B[4][4];
  #pragma unroll
  for (int ks = 0; ks < 4; ++ks)
    #pragma unroll
    for (int jn = 0; jn < 4; ++jn)
      B[ks][jn] = *(const bf16x8*)&vFrag[(((ks * 16 + w * 4 + jn) * 64) + lane) * 8];

  // bias, held all-kernel (reused by all 8 images)
  float bv[2][4][4];
  #pragma unroll
  for (int mt = 0; mt < 2; ++mt)
    #pragma unroll
    for (int jn = 0; jn < 4; ++jn)
      #pragma unroll
      for (int i = 0; i < 4; ++i) {
        int px = chunk * 32 + mt * 16 + g * 4 + i;
        bv[mt][jn][i] = bias[(size_t)px * F_ + (w * 4 + jn) * 16 + lm];
      }

  for (int img = 0; img < 8; ++img) {
    const unsigned short* zb = z + ((size_t)img * NPIX + chunk * 32) * ZSTR;
    bf16x8 A[2][4];
    #pragma unroll
    for (int mt = 0; mt < 2; ++mt)
      #pragma unroll
      for (int ks = 0; ks < 4; ++ks)
        A[mt][ks] = *(const bf16x8*)&zb[(size_t)(mt * 16 + lm) * ZSTR + ks * 32 + g * 8];

    f32x4 acc[2][4] = {};
    #pragma unroll
    for (int ks = 0; ks < 4; ++ks)
      #pragma unroll
      for (int jn = 0; jn < 4; ++jn) {
        acc[0][jn] = __builtin_amdgcn_mfma_f32_16x16x32_bf16(A[0][ks], B[ks][jn], acc[0][jn], 0, 0, 0);
        acc[1][jn] = __builtin_amdgcn_mfma_f32_16x16x32_bf16(A[1][ks], B[ks][jn], acc[1][jn], 0, 0, 0);
      }

    float* ob = out + ((size_t)img * NPIX + chunk * 32) * F_;
    #pragma unroll
    for (int mt = 0; mt < 2; ++mt)
      #pragma unroll
      for (int i = 0; i < 4; ++i) {
        size_t pbase = (size_t)(mt * 16 + g * 4 + i) * F_;
        #pragma unroll
        for (int jn = 0; jn < 4; ++jn) {
          float v = fmaxf(acc[mt][jn][i] + bv[mt][jn][i], 0.f);
          ob[pbase + (w * 4 + jn) * 16 + lm] = v;
        }
      }
  }
}

// ---------- Fallback: R3 fused kernel (380 us), used if ws too small ----------
__global__ __launch_bounds__(256, 4) void fused_kernel(
    const float* __restrict__ x,
    const unsigned short* __restrict__ uFrag,
    const unsigned short* __restrict__ vFrag,
    const float* __restrict__ bias,
    float* __restrict__ out) {
  __shared__ unsigned short xt[4 * 34 * 64];
  __shared__ unsigned short z1[64 * 128];

  int bid = blockIdx.x;
  int bb = bid & 7;
  int t2 = bid >> 3;
  int tw = t2 % 7;
  int th = t2 / 7;
  int h0 = th * 2, w0 = tw * 32;
  int tid = threadIdx.x;
  int lane = tid & 63, wid = tid >> 6;
  int wm = wid & 1, wn = wid >> 1;
  int g = lane >> 4, lm = lane & 15;

  const float* xb = x + (size_t)bb * (H_ * W_ * C_);
  #pragma unroll
  for (int it = 0; it < 5; ++it) {
    int i = tid + it * 256;
    if (i < 1088) {
      int row34 = i >> 3, c8 = i & 7;
      int r = row34 / 34;
      int ww = row34 - r * 34;
      int h = h0 - 1 + r, w = w0 - 1 + ww;
      bf16x8 sv;
      if (h >= 0 && h < H_ && w >= 0 && w < W_) {
        const float* p = xb + ((size_t)(h * W_ + w)) * C_ + c8 * 8;
        float4 f0 = *(const float4*)p;
        float4 f1 = *(const float4*)(p + 4);
        sv[0] = (short)f2bf(f0.x); sv[1] = (short)f2bf(f0.y);
        sv[2] = (short)f2bf(f0.z); sv[3] = (short)f2bf(f0.w);
        sv[4] = (short)f2bf(f1.x); sv[5] = (short)f2bf(f1.y);
        sv[6] = (short)f2bf(f1.z); sv[7] = (short)f2bf(f1.w);
      } else {
        sv = (bf16x8){0, 0, 0, 0, 0, 0, 0, 0};
      }
      *(bf16x8*)&xt[row34 * 64 + ((c8 ^ (row34 & 7)) << 3)] = sv;
    }
  }

  int rowoff[2][4];
  #pragma unroll
  for (int t = 0; t < 2; ++t)
    #pragma unroll
    for (int i = 0; i < 4; ++i) {
      int mrow = (2 * wm + t) * 16 + g * 4 + i;
      rowoff[t][i] = (h0 + (mrow >> 5)) * W_ + (w0 + (mrow & 31));
    }

  __syncthreads();

  float bv0[2][4][4];
  #pragma unroll
  for (int t = 0; t < 2; ++t)
    #pragma unroll
    for (int j = 0; j < 4; ++j)
      #pragma unroll
      for (int i = 0; i < 4; ++i)
        bv0[t][j][i] = bias[(size_t)rowoff[t][i] * F_ + (wn * 8 + j) * 16 + lm];

  f32x4 acc1[2][4] = {};
  #pragma unroll
  for (int ks = 0; ks < 18; ++ks) {
    int cell = ks >> 1;
    int kh = cell / 3, kw = cell - kh * 3;
    int c0c = (ks & 1) * 4;
    bf16x8 a[2];
    #pragma unroll
    for (int t = 0; t < 2; ++t) {
      int mrow = (2 * wm + t) * 16 + lm;
      int row34 = ((mrow >> 5) + kh) * 34 + (mrow & 31) + kw;
      int chunk = (c0c + g) ^ (row34 & 7);
      a[t] = *(const bf16x8*)&xt[row34 * 64 + chunk * 8];
    }
    #pragma unroll
    for (int j = 0; j < 4; ++j) {
      bf16x8 bq = *(const bf16x8*)&uFrag[(((ks * 8 + wn * 4 + j) * 64) + lane) * 8];
      acc1[0][j] = __builtin_amdgcn_mfma_f32_16x16x32_bf16(a[0], bq, acc1[0][j], 0, 0, 0);
      acc1[1][j] = __builtin_amdgcn_mfma_f32_16x16x32_bf16(a[1], bq, acc1[1][j], 0, 0, 0);
    }
  }

  #pragma unroll
  for (int t = 0; t < 2; ++t)
    #pragma unroll
    for (int j = 0; j < 4; ++j) {
      int col = (wn * 4 + j) * 16 + lm;
      #pragma unroll
      for (int i = 0; i < 4; ++i) {
        int row = (2 * wm + t) * 16 + g * 4 + i;
        z1[row * 128 + (((col >> 3) ^ (row & 7)) << 3) + (col & 7)] = f2bf(acc1[t][j][i]);
      }
    }
  __syncthreads();

  float bv1[2][4][4];
  #pragma unroll
  for (int t = 0; t < 2; ++t)
    #pragma unroll
    for (int j = 0; j < 4; ++j)
      #pragma unroll
      for (int i = 0; i < 4; ++i)
        bv1[t][j][i] = bias[(size_t)rowoff[t][i] * F_ + (wn * 8 + 4 + j) * 16 + lm];

  float* ob = out + (size_t)bb * (H_ * W_ * F_);

  {
    f32x4 acc2[2][4] = {};
    #pragma unroll
    for (int ks = 0; ks < 4; ++ks) {
      bf16x8 a2[2];
      #pragma unroll
      for (int t = 0; t < 2; ++t) {
        int row = (2 * wm + t) * 16 + lm;
        int chunk = (ks * 4 + g) ^ (row & 7);
        a2[t] = *(const bf16x8*)&z1[row * 128 + chunk * 8];
      }
      #pragma unroll
      for (int j = 0; j < 4; ++j) {
        bf16x8 bq = *(const bf16x8*)&vFrag[(((ks * 16 + wn * 8 + j) * 64) + lane) * 8];
        acc2[0][j] = __builtin_amdgcn_mfma_f32_16x16x32_bf16(a2[0], bq, acc2[0][j], 0, 0, 0);
        acc2[1][j] = __builtin_amdgcn_mfma_f32_16x16x32_bf16(a2[1], bq, acc2[1][j], 0, 0, 0);
      }
    }
    #pragma unroll
    for (int t = 0; t < 2; ++t)
      #pragma unroll
      for (int j = 0; j < 4; ++j) {
        int f = (wn * 8 + j) * 16 + lm;
        #pragma unroll
        for (int i = 0; i < 4; ++i) {
          float v = fmaxf(acc2[t][j][i] + bv0[t][j][i], 0.f);
          __builtin_nontemporal_store(v, &ob[(size_t)rowoff[t][i] * F_ + f]);
        }
      }
  }
  {
    f32x4 acc2[2][4] = {};
    #pragma unroll
    for (int ks = 0; ks < 4; ++ks) {
      bf16x8 a2[2];
      #pragma unroll
      for (int t = 0; t < 2; ++t) {
        int row = (2 * wm + t) * 16 + lm;
        int chunk = (ks * 4 + g) ^ (row & 7);
        a2[t] = *(const bf16x8*)&z1[row * 128 + chunk * 8];
      }
      #pragma unroll
      for (int j = 0; j < 4; ++j) {
        bf16x8 bq = *(const bf16x8*)&vFrag[(((ks * 16 + wn * 8 + 4 + j) * 64) + lane) * 8];
        acc2[0][j] = __builtin_amdgcn_mfma_f32_16x16x32_bf16(a2[0], bq, acc2[0][j], 0, 0, 0);
        acc2[1][j] = __builtin_amdgcn_mfma_f32_16x16x32_bf16(a2[1], bq, acc2[1][j], 0, 0, 0);
      }
    }
    #pragma unroll
    for (int t = 0; t < 2; ++t)
      #pragma unroll
      for (int j = 0; j < 4; ++j) {
        int f = (wn * 8 + 4 + j) * 16 + lm;
        #pragma unroll
        for (int i = 0; i < 4; ++i) {
          float v = fmaxf(acc2[t][j][i] + bv1[t][j][i], 0.f);
          __builtin_nontemporal_store(v, &ob[(size_t)rowoff[t][i] * F_ + f]);
        }
      }
  }
}

extern "C" void kernel_launch(void* const* d_in, const int* in_sizes, int n_in,
                              void* d_out, int out_size, void* d_ws, size_t ws_size,
                              hipStream_t stream) {
  const float* x     = (const float*)d_in[0];
  const float* S     = (const float*)d_in[3];
  const float* Unp1  = (const float*)d_in[5];
  const float* Vtnp1 = (const float*)d_in[7];
  const float* bias  = (const float*)d_in[8];
  float* out = (float*)d_out;

  unsigned short* uFrag = (unsigned short*)d_ws;                         // 147456 B
  unsigned short* vFrag = (unsigned short*)((char*)d_ws + 147456);       // 65536 B
  unsigned short* zbuf  = (unsigned short*)((char*)d_ws + 212992);       // 102760448 B
  const size_t NEED = 212992 + (size_t)8 * NPIX * ZSTR * 2;

  hipLaunchKernelGGL(prep_kernel, dim3(416), dim3(256), 0, stream,
                     Unp1, S, Vtnp1, uFrag, vFrag);
  if (ws_size >= NEED) {
    hipLaunchKernelGGL(g1_kernel, dim3(8 * 112 * 7), dim3(256), 0, stream,
                       x, uFrag, zbuf);
    hipLaunchKernelGGL(g2_kernel, dim3(1568), dim3(256), 0, stream,
                       zbuf, vFrag, bias, out);
  } else {
    hipLaunchKernelGGL(fused_kernel, dim3(8 * 112 * 7), dim3(256), 0, stream,
                       x, uFrag, vFrag, bias, out);
  }
}

// Round 10
// 668.483 us; speedup vs baseline: 2.9664x; 1.1007x over previous
//
#include <hip/hip_runtime.h>
#include <hip/hip_bf16.h>

#define H_ 224
#define W_ 224
#define C_ 64
#define F_ 256
#define NPIX 50176      // H_*W_
#define ZSTR 128        // z row stride (elements)

typedef __attribute__((ext_vector_type(8))) short bf16x8;
typedef __attribute__((ext_vector_type(4))) float f32x4;

__device__ __forceinline__ unsigned short f2bf(float f) {
  union { float f; unsigned int u; } c; c.f = f;
  unsigned int u = c.u;
  return (unsigned short)((u + 0x7fffu + ((u >> 16) & 1u)) >> 16);
}

// Pre-pack U2 = Unp1 @ S into MFMA B-fragment layout [18][8][64][8] (N padded to 128),
// and Vt into [4][16][64][8] (K padded to 128).  (verified R2)
__global__ __launch_bounds__(256) void prep_kernel(
    const float* __restrict__ Unp1, const float* __restrict__ S,
    const float* __restrict__ Vt,
    unsigned short* __restrict__ uFrag, unsigned short* __restrict__ vFrag) {
  int u = blockIdx.x * 256 + threadIdx.x;
  if (u < 576 * 128) {
    int k = u >> 7;       // 0..575
    int n = u & 127;      // 0..127
    float acc = 0.f;
    if (n < 100) {
      for (int q = 0; q < 100; ++q)
        acc += Unp1[k * 100 + q] * S[q * 100 + n];
    }
    int ks = k >> 5, kk = k & 31, g = kk >> 3, j = kk & 7;
    int nt = n >> 4, lm = n & 15;
    uFrag[(((ks * 8 + nt) * 64) + g * 16 + lm) * 8 + j] = f2bf(acc);
  } else {
    int u2 = u - 576 * 128;
    if (u2 < 4 * 16 * 64 * 8) {
      int j = u2 & 7;
      int lane = (u2 >> 3) & 63;
      int nt = (u2 >> 9) & 15;
      int ks = u2 >> 13;
      int k = ks * 32 + (lane >> 4) * 8 + j;
      int n = nt * 16 + (lane & 15);
      float v = (k < 100) ? Vt[k * 256 + n] : 0.f;
      vFrag[u2] = f2bf(v);
    }
  }
}

// ---------- Kernel A: z = patches @ U2 (bf16 out, cols 100..127 = 0) ----------
// M-major waves: wave wn owns all 64 rows x N-cols [wn*32, wn*32+32).
// B-fragment L2 loads: 36/wave (2-deep pipelined), A via LDS.
__global__ __launch_bounds__(256, 4) void g1_kernel(
    const float* __restrict__ x,
    const unsigned short* __restrict__ uFrag,
    unsigned short* __restrict__ z) {
  __shared__ unsigned short xt[4 * 34 * 64];   // halo tile, XOR-swizzled
  __shared__ unsigned short z1[64 * 128];      // result staging, XOR-swizzled

  int bid = blockIdx.x;
  int tw = bid % 7;
  int th = (bid / 7) % 112;
  int bb = bid / 784;                  // bb slowest: neighbors share x halo
  int h0 = th * 2, w0 = tw * 32;
  int tid = threadIdx.x;
  int lane = tid & 63, wn = tid >> 6;  // wn = N-quarter
  int g = lane >> 4, lm = lane & 15;

  // ---- stage x halo tile -> LDS bf16 (verified R2) ----
  const float* xb = x + (size_t)bb * (H_ * W_ * C_);
  #pragma unroll
  for (int it = 0; it < 5; ++it) {
    int i = tid + it * 256;
    if (i < 1088) {
      int row34 = i >> 3, c8 = i & 7;
      int r = row34 / 34;
      int ww = row34 - r * 34;
      int h = h0 - 1 + r, w = w0 - 1 + ww;
      bf16x8 sv;
      if (h >= 0 && h < H_ && w >= 0 && w < W_) {
        const float* p = xb + ((size_t)(h * W_ + w)) * C_ + c8 * 8;
        float4 f0 = *(const float4*)p;
        float4 f1 = *(const float4*)(p + 4);
        sv[0] = (short)f2bf(f0.x); sv[1] = (short)f2bf(f0.y);
        sv[2] = (short)f2bf(f0.z); sv[3] = (short)f2bf(f0.w);
        sv[4] = (short)f2bf(f1.x); sv[5] = (short)f2bf(f1.y);
        sv[6] = (short)f2bf(f1.z); sv[7] = (short)f2bf(f1.w);
      } else {
        sv = (bf16x8){0, 0, 0, 0, 0, 0, 0, 0};
      }
      *(bf16x8*)&xt[row34 * 64 + ((c8 ^ (row34 & 7)) << 3)] = sv;
    }
  }
  __syncthreads();

  // ---- GEMM1: 4 m-frags x 2 n-frags per wave, 2-deep B prefetch ----
  f32x4 acc1[4][2] = {};
  {
    bf16x8 bq[2][2];                  // [parity][jn], no copies -> no folding
    #pragma unroll
    for (int jn = 0; jn < 2; ++jn)
      bq[0][jn] = *(const bf16x8*)&uFrag[(((0 * 8 + wn * 2 + jn) * 64) + lane) * 8];
    #pragma unroll
    for (int ks = 0; ks < 18; ++ks) {
      int cur = ks & 1, nxt = cur ^ 1;
      if (ks < 17) {
        #pragma unroll
        for (int jn = 0; jn < 2; ++jn)
          bq[nxt][jn] = *(const bf16x8*)&uFrag[((((ks + 1) * 8 + wn * 2 + jn) * 64) + lane) * 8];
      }
      int cell = ks >> 1;
      int kh = cell / 3, kw = cell - kh * 3;
      int c0c = (ks & 1) * 4;
      bf16x8 a[4];
      #pragma unroll
      for (int mf = 0; mf < 4; ++mf) {
        int mrow = mf * 16 + lm;
        int dh = mrow >> 5, dw = mrow & 31;
        int row34 = (dh + kh) * 34 + dw + kw;
        int chunk = (c0c + g) ^ (row34 & 7);
        a[mf] = *(const bf16x8*)&xt[row34 * 64 + chunk * 8];
      }
      #pragma unroll
      for (int mf = 0; mf < 4; ++mf)
        #pragma unroll
        for (int jn = 0; jn < 2; ++jn)
          acc1[mf][jn] = __builtin_amdgcn_mfma_f32_16x16x32_bf16(a[mf], bq[cur][jn], acc1[mf][jn], 0, 0, 0);
    }
  }

  // ---- acc -> z1 LDS (bf16, swizzled) ----
  #pragma unroll
  for (int mf = 0; mf < 4; ++mf) {
    #pragma unroll
    for (int jn = 0; jn < 2; ++jn) {
      int col = (wn * 2 + jn) * 16 + lm;
      #pragma unroll
      for (int i = 0; i < 4; ++i) {
        int row = mf * 16 + g * 4 + i;
        z1[row * 128 + (((col >> 3) ^ (row & 7)) << 3) + (col & 7)] = f2bf(acc1[mf][jn][i]);
      }
    }
  }
  __syncthreads();

  // ---- cooperative z1 -> z (coalesced 16B stores) ----
  #pragma unroll
  for (int it = 0; it < 4; ++it) {
    int i = tid + it * 256;            // 0..1023
    int row = i >> 4, c8 = i & 15;
    bf16x8 v = *(const bf16x8*)&z1[row * 128 + ((c8 ^ (row & 7)) << 3)];
    int pixel = (h0 + (row >> 5)) * W_ + w0 + (row & 31);
    *(bf16x8*)&z[((size_t)bb * NPIX + pixel) * ZSTR + c8 * 8] = v;
  }
}

// ---------- Kernel B: out = relu(z @ Vt + bias) ----------
// Block = 32 pixels x 256 f, loops 8 images. B-frags + bias in registers.
__global__ __launch_bounds__(256, 2) void g2_kernel(
    const unsigned short* __restrict__ z,
    const unsigned short* __restrict__ vFrag,
    const float* __restrict__ bias,
    float* __restrict__ out) {
  int chunk = blockIdx.x;              // 0..1567, 32 consecutive pixels
  int tid = threadIdx.x;
  int lane = tid & 63, w = tid >> 6;   // wave -> f-range [w*64, w*64+64)
  int g = lane >> 4, lm = lane & 15;

  // B fragments, held all-kernel: 16 x 16B from L2
  bf16x8 B[4][4];
  #pragma unroll
  for (int ks = 0; ks < 4; ++ks)
    #pragma unroll
    for (int jn = 0; jn < 4; ++jn)
      B[ks][jn] = *(const bf16x8*)&vFrag[(((ks * 16 + w * 4 + jn) * 64) + lane) * 8];

  // bias, held all-kernel (reused by all 8 images)
  float bv[2][4][4];
  #pragma unroll
  for (int mt = 0; mt < 2; ++mt)
    #pragma unroll
    for (int jn = 0; jn < 4; ++jn)
      #pragma unroll
      for (int i = 0; i < 4; ++i) {
        int px = chunk * 32 + mt * 16 + g * 4 + i;
        bv[mt][jn][i] = bias[(size_t)px * F_ + (w * 4 + jn) * 16 + lm];
      }

  #pragma unroll 2
  for (int img = 0; img < 8; ++img) {
    const unsigned short* zb = z + ((size_t)img * NPIX + chunk * 32) * ZSTR;
    bf16x8 A[2][4];
    #pragma unroll
    for (int mt = 0; mt < 2; ++mt)
      #pragma unroll
      for (int ks = 0; ks < 4; ++ks)
        A[mt][ks] = *(const bf16x8*)&zb[(size_t)(mt * 16 + lm) * ZSTR + ks * 32 + g * 8];

    f32x4 acc[2][4] = {};
    #pragma unroll
    for (int ks = 0; ks < 4; ++ks)
      #pragma unroll
      for (int jn = 0; jn < 4; ++jn) {
        acc[0][jn] = __builtin_amdgcn_mfma_f32_16x16x32_bf16(A[0][ks], B[ks][jn], acc[0][jn], 0, 0, 0);
        acc[1][jn] = __builtin_amdgcn_mfma_f32_16x16x32_bf16(A[1][ks], B[ks][jn], acc[1][jn], 0, 0, 0);
      }

    float* ob = out + ((size_t)img * NPIX + chunk * 32) * F_;
    #pragma unroll
    for (int mt = 0; mt < 2; ++mt)
      #pragma unroll
      for (int i = 0; i < 4; ++i) {
        size_t pbase = (size_t)(mt * 16 + g * 4 + i) * F_;
        #pragma unroll
        for (int jn = 0; jn < 4; ++jn) {
          float v = fmaxf(acc[mt][jn][i] + bv[mt][jn][i], 0.f);
          ob[pbase + (w * 4 + jn) * 16 + lm] = v;
        }
      }
  }
}

// ---------- Fallback: R3 fused kernel, used if ws too small ----------
__global__ __launch_bounds__(256, 4) void fused_kernel(
    const float* __restrict__ x,
    const unsigned short* __restrict__ uFrag,
    const unsigned short* __restrict__ vFrag,
    const float* __restrict__ bias,
    float* __restrict__ out) {
  __shared__ unsigned short xt[4 * 34 * 64];
  __shared__ unsigned short z1[64 * 128];

  int bid = blockIdx.x;
  int bb = bid & 7;
  int t2 = bid >> 3;
  int tw = t2 % 7;
  int th = t2 / 7;
  int h0 = th * 2, w0 = tw * 32;
  int tid = threadIdx.x;
  int lane = tid & 63, wid = tid >> 6;
  int wm = wid & 1, wn = wid >> 1;
  int g = lane >> 4, lm = lane & 15;

  const float* xb = x + (size_t)bb * (H_ * W_ * C_);
  #pragma unroll
  for (int it = 0; it < 5; ++it) {
    int i = tid + it * 256;
    if (i < 1088) {
      int row34 = i >> 3, c8 = i & 7;
      int r = row34 / 34;
      int ww = row34 - r * 34;
      int h = h0 - 1 + r, w = w0 - 1 + ww;
      bf16x8 sv;
      if (h >= 0 && h < H_ && w >= 0 && w < W_) {
        const float* p = xb + ((size_t)(h * W_ + w)) * C_ + c8 * 8;
        float4 f0 = *(const float4*)p;
        float4 f1 = *(const float4*)(p + 4);
        sv[0] = (short)f2bf(f0.x); sv[1] = (short)f2bf(f0.y);
        sv[2] = (short)f2bf(f0.z); sv[3] = (short)f2bf(f0.w);
        sv[4] = (short)f2bf(f1.x); sv[5] = (short)f2bf(f1.y);
        sv[6] = (short)f2bf(f1.z); sv[7] = (short)f2bf(f1.w);
      } else {
        sv = (bf16x8){0, 0, 0, 0, 0, 0, 0, 0};
      }
      *(bf16x8*)&xt[row34 * 64 + ((c8 ^ (row34 & 7)) << 3)] = sv;
    }
  }

  int rowoff[2][4];
  #pragma unroll
  for (int t = 0; t < 2; ++t)
    #pragma unroll
    for (int i = 0; i < 4; ++i) {
      int mrow = (2 * wm + t) * 16 + g * 4 + i;
      rowoff[t][i] = (h0 + (mrow >> 5)) * W_ + (w0 + (mrow & 31));
    }

  __syncthreads();

  float bv0[2][4][4];
  #pragma unroll
  for (int t = 0; t < 2; ++t)
    #pragma unroll
    for (int j = 0; j < 4; ++j)
      #pragma unroll
      for (int i = 0; i < 4; ++i)
        bv0[t][j][i] = bias[(size_t)rowoff[t][i] * F_ + (wn * 8 + j) * 16 + lm];

  f32x4 acc1[2][4] = {};
  #pragma unroll
  for (int ks = 0; ks < 18; ++ks) {
    int cell = ks >> 1;
    int kh = cell / 3, kw = cell - kh * 3;
    int c0c = (ks & 1) * 4;
    bf16x8 a[2];
    #pragma unroll
    for (int t = 0; t < 2; ++t) {
      int mrow = (2 * wm + t) * 16 + lm;
      int row34 = ((mrow >> 5) + kh) * 34 + (mrow & 31) + kw;
      int chunk = (c0c + g) ^ (row34 & 7);
      a[t] = *(const bf16x8*)&xt[row34 * 64 + chunk * 8];
    }
    #pragma unroll
    for (int j = 0; j < 4; ++j) {
      bf16x8 bq = *(const bf16x8*)&uFrag[(((ks * 8 + wn * 4 + j) * 64) + lane) * 8];
      acc1[0][j] = __builtin_amdgcn_mfma_f32_16x16x32_bf16(a[0], bq, acc1[0][j], 0, 0, 0);
      acc1[1][j] = __builtin_amdgcn_mfma_f32_16x16x32_bf16(a[1], bq, acc1[1][j], 0, 0, 0);
    }
  }

  #pragma unroll
  for (int t = 0; t < 2; ++t)
    #pragma unroll
    for (int j = 0; j < 4; ++j) {
      int col = (wn * 4 + j) * 16 + lm;
      #pragma unroll
      for (int i = 0; i < 4; ++i) {
        int row = (2 * wm + t) * 16 + g * 4 + i;
        z1[row * 128 + (((col >> 3) ^ (row & 7)) << 3) + (col & 7)] = f2bf(acc1[t][j][i]);
      }
    }
  __syncthreads();

  float bv1[2][4][4];
  #pragma unroll
  for (int t = 0; t < 2; ++t)
    #pragma unroll
    for (int j = 0; j < 4; ++j)
      #pragma unroll
      for (int i = 0; i < 4; ++i)
        bv1[t][j][i] = bias[(size_t)rowoff[t][i] * F_ + (wn * 8 + 4 + j) * 16 + lm];

  float* ob = out + (size_t)bb * (H_ * W_ * F_);

  {
    f32x4 acc2[2][4] = {};
    #pragma unroll
    for (int ks = 0; ks < 4; ++ks) {
      bf16x8 a2[2];
      #pragma unroll
      for (int t = 0; t < 2; ++t) {
        int row = (2 * wm + t) * 16 + lm;
        int chunk = (ks * 4 + g) ^ (row & 7);
        a2[t] = *(const bf16x8*)&z1[row * 128 + chunk * 8];
      }
      #pragma unroll
      for (int j = 0; j < 4; ++j) {
        bf16x8 bq = *(const bf16x8*)&vFrag[(((ks * 16 + wn * 8 + j) * 64) + lane) * 8];
        acc2[0][j] = __builtin_amdgcn_mfma_f32_16x16x32_bf16(a2[0], bq, acc2[0][j], 0, 0, 0);
        acc2[1][j] = __builtin_amdgcn_mfma_f32_16x16x32_bf16(a2[1], bq, acc2[1][j], 0, 0, 0);
      }
    }
    #pragma unroll
    for (int t = 0; t < 2; ++t)
      #pragma unroll
      for (int j = 0; j < 4; ++j) {
        int f = (wn * 8 + j) * 16 + lm;
        #pragma unroll
        for (int i = 0; i < 4; ++i) {
          float v = fmaxf(acc2[t][j][i] + bv0[t][j][i], 0.f);
          __builtin_nontemporal_store(v, &ob[(size_t)rowoff[t][i] * F_ + f]);
        }
      }
  }
  {
    f32x4 acc2[2][4] = {};
    #pragma unroll
    for (int ks = 0; ks < 4; ++ks) {
      bf16x8 a2[2];
      #pragma unroll
      for (int t = 0; t < 2; ++t) {
        int row = (2 * wm + t) * 16 + lm;
        int chunk = (ks * 4 + g) ^ (row & 7);
        a2[t] = *(const bf16x8*)&z1[row * 128 + chunk * 8];
      }
      #pragma unroll
      for (int j = 0; j < 4; ++j) {
        bf16x8 bq = *(const bf16x8*)&vFrag[(((ks * 16 + wn * 8 + 4 + j) * 64) + lane) * 8];
        acc2[0][j] = __builtin_amdgcn_mfma_f32_16x16x32_bf16(a2[0], bq, acc2[0][j], 0, 0, 0);
        acc2[1][j] = __builtin_amdgcn_mfma_f32_16x16x32_bf16(a2[1], bq, acc2[1][j], 0, 0, 0);
      }
    }
    #pragma unroll
    for (int t = 0; t < 2; ++t)
      #pragma unroll
      for (int j = 0; j < 4; ++j) {
        int f = (wn * 8 + 4 + j) * 16 + lm;
        #pragma unroll
        for (int i = 0; i < 4; ++i) {
          float v = fmaxf(acc2[t][j][i] + bv1[t][j][i], 0.f);
          __builtin_nontemporal_store(v, &ob[(size_t)rowoff[t][i] * F_ + f]);
        }
      }
  }
}

extern "C" void kernel_launch(void* const* d_in, const int* in_sizes, int n_in,
                              void* d_out, int out_size, void* d_ws, size_t ws_size,
                              hipStream_t stream) {
  const float* x     = (const float*)d_in[0];
  const float* S     = (const float*)d_in[3];
  const float* Unp1  = (const float*)d_in[5];
  const float* Vtnp1 = (const float*)d_in[7];
  const float* bias  = (const float*)d_in[8];
  float* out = (float*)d_out;

  unsigned short* uFrag = (unsigned short*)d_ws;                         // 147456 B
  unsigned short* vFrag = (unsigned short*)((char*)d_ws + 147456);       // 65536 B
  unsigned short* zbuf  = (unsigned short*)((char*)d_ws + 212992);       // 102760448 B
  const size_t NEED = 212992 + (size_t)8 * NPIX * ZSTR * 2;

  hipLaunchKernelGGL(prep_kernel, dim3(416), dim3(256), 0, stream,
                     Unp1, S, Vtnp1, uFrag, vFrag);
  if (ws_size >= NEED) {
    hipLaunchKernelGGL(g1_kernel, dim3(8 * 112 * 7), dim3(256), 0, stream,
                       x, uFrag, zbuf);
    hipLaunchKernelGGL(g2_kernel, dim3(1568), dim3(256), 0, stream,
                       zbuf, vFrag, bias, out);
  } else {
    hipLaunchKernelGGL(fused_kernel, dim3(8 * 112 * 7), dim3(256), 0, stream,
                       x, uFrag, vFrag, bias, out);
  }
}